// Round 3
// baseline (8993.555 us; speedup 1.0000x reference)
//
#include <hip/hip_runtime.h>
#include <cmath>

typedef _Float16 f16;
typedef _Float16 half8 __attribute__((ext_vector_type(8)));
typedef float floatx4 __attribute__((ext_vector_type(4)));
typedef unsigned u32x4 __attribute__((ext_vector_type(4)));

#define NT 512
#define NB 64
#define NH 512
#define NG 2048
#define CHUNK 128

__device__ inline float sigf(float x) { return 1.0f / (1.0f + __expf(-x)); }
__device__ inline float tanhfast(float x) { return 2.0f / (1.0f + __expf(-2.0f * x)) - 1.0f; }

__device__ inline void load_lds16(const f16* g, f16* l) {
  __builtin_amdgcn_global_load_lds(
      (__attribute__((address_space(1))) void*)g,
      (__attribute__((address_space(3))) void*)l, 16, 0, 0);
}

// ---------------------------------------------------------------- meta
__global__ void prep_meta(const int* __restrict__ bs_raw, int* __restrict__ lens,
                          int* __restrict__ cum) {
  __shared__ int sbs[NT];
  int stride = (bs_raw[1] == 0) ? 2 : 1;  // int64 arrives as stride-2 int32
  for (int i = threadIdx.x; i < NT; i += 256) sbs[i] = bs_raw[i * stride];
  __syncthreads();
  for (int b = threadIdx.x; b < NB; b += 256) {
    int n = 0;
    for (int t = 0; t < NT; ++t) n += (sbs[t] > b);
    lens[b] = n;
  }
  if (threadIdx.x == 0) {
    int run = 0;
    for (int t = 0; t < NT; ++t) { cum[t] = run; run += sbs[t]; }
  }
}

// ---------------------------------------------------------------- unpack
__global__ void scatter_rows(const float* __restrict__ data, const int* __restrict__ pidx,
                             f16* __restrict__ X0) {
  int r = blockIdx.x;
  int row = pidx[r];
  const float* src = data + (size_t)r * 512;
  f16* dst = X0 + (size_t)row * 512;
  for (int k = threadIdx.x; k < 512; k += 256) dst[k] = (f16)src[k];
}

__global__ void f32_to_f16(const float* __restrict__ in, f16* __restrict__ out, size_t n) {
  size_t i = (size_t)blockIdx.x * 256 + threadIdx.x;
  size_t stride = (size_t)gridDim.x * 256;
  for (; i < n; i += stride) out[i] = (f16)in[i];
}

// ---------------------------------------------------------------- per-layer h/c init
// Writes tagged h words (epoch = layer*NT) into parity-0 (agent scope) and
// primes parity-0 ready counters. Parity-1 leftovers from the previous layer
// are <= layer*NT, so they can never false-positive (epochs monotonic).
__global__ void init_h(const float* __restrict__ h0, const float* __restrict__ c0,
                       float* __restrict__ hsave, float* __restrict__ csave,
                       unsigned* __restrict__ ht, unsigned* __restrict__ ctr, int layer) {
  int idx = blockIdx.x * 256 + threadIdx.x;  // 2*64*512 = 65536
  int d = idx >> 15, rem = idx & 32767;
  float hv = h0[(size_t)(2 * layer + d) * NB * NH + rem];
  float cv = c0[(size_t)(2 * layer + d) * NB * NH + rem];
  hsave[idx] = hv;
  csave[idx] = cv;
  union { f16 f; unsigned short s; } hc; hc.f = (f16)hv;
  unsigned word = ((unsigned)(layer * NT) << 16) | hc.s;
  __hip_atomic_store(ht + (size_t)d * NB * NH + rem, word,
                     __ATOMIC_RELAXED, __HIP_MEMORY_SCOPE_AGENT);
  if (blockIdx.x == 0) {
    // parity-0 ready counters: slots [0][g][w] (w<8 used; rest harmless)
    __hip_atomic_store(ctr + threadIdx.x, (unsigned)(layer * NT),
                       __ATOMIC_RELAXED, __HIP_MEMORY_SCOPE_AGENT);
  }
}

// ---------------------------------------------------------------- gx GEMM (one chunk)
__global__ __launch_bounds__(256) void gemm_gx(const f16* __restrict__ A,
                                               const f16* __restrict__ W,
                                               const float* __restrict__ bias,
                                               const int* __restrict__ lens,
                                               f16* __restrict__ gxc, int K, int c0) {
  const int d = blockIdx.z;
  const int m0 = blockIdx.y * 128;
  const int n0 = blockIdx.x * 128;
  const f16* Wd = W + (size_t)d * NG * K;

  __shared__ __align__(16) f16 As[128 * 32];
  __shared__ __align__(16) f16 Bs[128 * 32];

  const int tid = threadIdx.x, lane = tid & 63, wv = tid >> 6;
  const int wm = wv >> 1, wn = wv & 1;
  const int lrow = lane >> 2, lcol = (lane & 3) * 8;
  const int q = lane >> 4, nn = lane & 15;

  const f16* aptr[2];
  const f16* bptr[2];
#pragma unroll
  for (int i = 0; i < 2; ++i) {
    int ch = wv * 2 + i;
    int m = m0 + ch * 16 + lrow;  // chunk-local row = ct*64 + b
    int t = c0 + (m >> 6), b = m & 63;
    int tt = t;
    if (d) { tt = lens[b] - 1 - t; tt = tt < 0 ? 0 : (tt > NT - 1 ? NT - 1 : tt); }
    aptr[i] = A + (size_t)(tt * NB + b) * K + lcol;
    bptr[i] = Wd + (size_t)(n0 + ch * 16 + lrow) * K + lcol;
  }

  floatx4 acc[4][4] = {};
  for (int k0 = 0; k0 < K; k0 += 32) {
    __syncthreads();
#pragma unroll
    for (int i = 0; i < 2; ++i) {
      int ch = wv * 2 + i;
      load_lds16(aptr[i] + k0, As + ch * 512);
      load_lds16(bptr[i] + k0, Bs + ch * 512);
    }
    __syncthreads();
    half8 a[4], b[4];
#pragma unroll
    for (int f = 0; f < 4; ++f) {
      a[f] = *(const half8*)(As + (wm * 64 + f * 16 + nn) * 32 + q * 8);
      b[f] = *(const half8*)(Bs + (wn * 64 + f * 16 + nn) * 32 + q * 8);
    }
#pragma unroll
    for (int fm = 0; fm < 4; ++fm)
#pragma unroll
      for (int fn = 0; fn < 4; ++fn)
        acc[fm][fn] = __builtin_amdgcn_mfma_f32_16x16x32_f16(a[fm], b[fn], acc[fm][fn], 0, 0, 0);
  }

  f16* gxd = gxc + (size_t)d * CHUNK * NB * NG;
#pragma unroll
  for (int fn = 0; fn < 4; ++fn) {
    int col = n0 + wn * 64 + fn * 16 + nn;
    float bv = bias[d * NG + col];
#pragma unroll
    for (int fm = 0; fm < 4; ++fm) {
      int mb = m0 + wm * 64 + fm * 16 + q * 4;
#pragma unroll
      for (int r = 0; r < 4; ++r)
        gxd[(size_t)(mb + r) * NG + col] = (f16)(acc[fm][fn][r] + bv);
    }
  }
}

// ---------------------------------------------------------------- recurrence (one chunk)
// 64 blocks x 1024 threads = 8 groups x 8 fat blocks; group g = (dir=g&1,
// 16-row slice bsl=g>>1), closed under h dataflow. Block w of a group owns
// j-columns [w*64, w*64+64). Fat blocks cut the per-step MALL poll traffic
// 4x (64 x 32KB = 2MB/step vs 8MB) and verify loads to 4 u64/thread.
// Sync = tagged-h words (epoch<<16 | f16 h), agent scope (proven protocol),
// pre-gated by per-producer ready counters ctr[par][g][w]. The ctr bump is
// RELEASE-ordered: every thread drains vmcnt(0) after its h publish, then a
// block barrier, then tid0 bumps -- so a consumer observing the bump finds
// all 1024 data words already visible (verify passes first try; tags remain
// the correctness proof regardless).
__global__ __launch_bounds__(1024) void lstm_rec(
    const f16* __restrict__ gxc, const f16* __restrict__ whh,
    const int* __restrict__ lens, const int* __restrict__ cum,
    float* __restrict__ hsave, float* __restrict__ csave,
    unsigned* __restrict__ ht, unsigned* __restrict__ ctr,
    f16* __restrict__ Y, float* __restrict__ outp,
    float* __restrict__ hT, float* __restrict__ cT,
    int c0, int mode, int layer) {
  const int tid = threadIdx.x, lane = tid & 63, wv = tid >> 6;  // wv in [0,16)
  const int g = blockIdx.x & 7, w = blockIdx.x >> 3;            // w in [0,8)
  const int dir = g & 1, bsl = g >> 1;
  const int q = lane >> 4, nn = lane & 15;

  const int maxlen = lens[bsl * 16];  // rows sorted desc: uniform group exit
  int nst = maxlen - c0;
  if (nst <= 0) return;
  if (nst > CHUNK) nst = CHUNK;

  // LDS: double-buffered extracted-A tile (16 rows x 512 k f16, packed u32,
  // row pad +4) and per-wave gate-transpose scratch.
  __shared__ __align__(16) unsigned As[2][16][260];
  __shared__ float s_g[16][16][17];

  const int jbase = w * 64 + wv * 4;
  const int coln = (nn >> 2) * NH + jbase + (nn & 3);
  const f16* whd = whh + (size_t)dir * NG * NH;
  half8 bf[16];
#pragma unroll
  for (int s = 0; s < 16; ++s)
    bf[s] = *(const half8*)(whd + (size_t)coln * NH + s * 32 + q * 8);

  const int b_e = bsl * 16 + nn;
  const int jglob = jbase + q;
  const int lene = lens[b_e];
  const int brow = bsl * 16 + q * 4;
  const int lidx = (dir * NB + b_e) * NH + jglob;
  float h = hsave[lidx], c = csave[lidx];

  const f16* gxd = gxc + (size_t)dir * CHUNK * NB * NG;
  const int ebase = layer * NT;  // epochs monotonic across chunks & layers

  for (int ct = 0; ct < nst; ++ct) {
    const int t = c0 + ct;
    const int e = ebase + t;      // tag required on consumed h
    const int par = t & 1;

    // gx loads issued early (HBM latency overlaps the gate wait)
    float gxv[4];
#pragma unroll
    for (int r = 0; r < 4; ++r)
      gxv[r] = (float)gxd[(size_t)(ct * NB + brow + r) * NG + coln];

    // ---- readiness gate: each wave spins on the 8 producer counters ----
    {
      const unsigned* cp = ctr + (size_t)par * 256 + (size_t)g * 32 + (lane & 7);
      int it = 0;
      for (;;) {
        unsigned cv = __hip_atomic_load(cp, __ATOMIC_RELAXED, __HIP_MEMORY_SCOPE_AGENT);
        if (__ballot((int)cv >= e) == ~0ull) break;
        if (++it > 100000) break;  // fail as wrong-answer, not hang
      }
    }

    // ---- data pass, tag-verified (release-ordered bump => ~1 iteration) ----
    // thread (wv,q,nn): row nn, packed-u32 words [wv*32+q*8, +8) = 4 u64
    const unsigned long long* p64 =
        (const unsigned long long*)(ht + ((size_t)(par * 2 + dir) * NB + bsl * 16 + nn) * NH) +
        (wv * 16 + q * 4);
    unsigned long long wb[4];
    {
      int it = 0;
      for (;;) {
#pragma unroll
        for (int i = 0; i < 4; ++i)
          wb[i] = __hip_atomic_load(p64 + i, __ATOMIC_RELAXED, __HIP_MEMORY_SCOPE_AGENT);
        unsigned tg = 0xffffu;
#pragma unroll
        for (int i = 0; i < 4; ++i) {
          tg &= (unsigned)(wb[i] >> 16) & 0xffffu;
          tg &= (unsigned)(wb[i] >> 48);
        }
        // words hold only epoch e or e-2 (ping-pong parity); AND(e-2, e) < e,
        // AND(all e) == e -> exact freshness test.
        if (__ballot(tg >= (unsigned)e) == ~0ull) break;
        if (++it > 50000) break;  // fail as wrong-answer, not hang
      }
    }

    // ---- extract f16 payloads -> LDS A tile ----
    {
      unsigned d0 = (unsigned)(wb[0] & 0xffffu) | ((unsigned)(wb[0] >> 32) << 16);
      unsigned d1 = (unsigned)(wb[1] & 0xffffu) | ((unsigned)(wb[1] >> 32) << 16);
      unsigned d2 = (unsigned)(wb[2] & 0xffffu) | ((unsigned)(wb[2] >> 32) << 16);
      unsigned d3 = (unsigned)(wb[3] & 0xffffu) | ((unsigned)(wb[3] >> 32) << 16);
      *(u32x4*)&As[par][nn][wv * 16 + q * 4] = (u32x4){d0, d1, d2, d3};
    }
    __syncthreads();  // (b) A tile complete

    // ---- MFMA: 16 k-slabs from LDS ----
    floatx4 acc0 = {0.f, 0.f, 0.f, 0.f}, acc1 = {0.f, 0.f, 0.f, 0.f};
#pragma unroll
    for (int s = 0; s < 8; ++s) {
      half8 a0 = *(const half8*)&As[par][nn][(2 * s) * 16 + q * 4];
      half8 a1 = *(const half8*)&As[par][nn][(2 * s + 1) * 16 + q * 4];
      acc0 = __builtin_amdgcn_mfma_f32_16x16x32_f16(a0, bf[2 * s], acc0, 0, 0, 0);
      acc1 = __builtin_amdgcn_mfma_f32_16x16x32_f16(a1, bf[2 * s + 1], acc1, 0, 0, 0);
    }
#pragma unroll
    for (int r4 = 0; r4 < 4; ++r4) s_g[wv][q * 4 + r4][nn] = acc0[r4] + acc1[r4] + gxv[r4];
    // s_g[wv] is wave-private: ds ordering (lgkmcnt) suffices, no barrier.

    const bool act = (t < lene);
    if (act) {
      float gi = s_g[wv][nn][q];
      float gf = s_g[wv][nn][4 + q];
      float gg = s_g[wv][nn][8 + q];
      float go = s_g[wv][nn][12 + q];
      c = sigf(gf) * c + sigf(gi) * tanhfast(gg);
      h = sigf(go) * tanhfast(c);
    }
    // ---- tagged publish ----
    union { f16 f; unsigned short s; } hc; hc.f = (f16)h;
    unsigned word = ((unsigned)(e + 1) << 16) | hc.s;
    __hip_atomic_store(ht + ((size_t)(((t + 1) & 1) * 2 + dir) * NB + b_e) * NH + jglob,
                       word, __ATOMIC_RELAXED, __HIP_MEMORY_SCOPE_AGENT);
    // ---- release-ordered ready bump: drain own stores, barrier, bump ----
    asm volatile("s_waitcnt vmcnt(0)" ::: "memory");
    __syncthreads();  // (c) all 1024 publishes at the point of coherence
    if (tid == 0)
      __hip_atomic_store(ctr + (size_t)(((t + 1) & 1) * 256 + g * 32 + w), (unsigned)(e + 1),
                         __ATOMIC_RELAXED, __HIP_MEMORY_SCOPE_AGENT);
    // Y / packed-out stores: fire-and-forget after the bump (drained next iter)
    if (mode == 0) {
      int tp = act ? (dir ? (lene - 1 - t) : t) : t;
      Y[(size_t)(tp * NB + b_e) * (2 * NH) + dir * NH + jglob] = act ? (f16)h : (f16)0.f;
    } else if (act) {
      int tp = dir ? (lene - 1 - t) : t;
      outp[(size_t)(cum[tp] + b_e) * (2 * NH) + dir * NH + jglob] = h;
    }
  }

  hsave[lidx] = h;
  csave[lidx] = c;
  const int sidx = ((2 * layer + dir) * NB + b_e) * NH + jglob;
  hT[sidx] = h;
  cT[sidx] = c;
}

// ---------------------------------------------------------------- host
extern "C" void kernel_launch(void* const* d_in, const int* in_sizes, int n_in,
                              void* d_out, int out_size, void* d_ws, size_t ws_size,
                              hipStream_t stream) {
  const float* data  = (const float*)d_in[0];
  const float* h0    = (const float*)d_in[1];
  const float* c0    = (const float*)d_in[2];
  const float* w_ih0 = (const float*)d_in[3];
  const float* w_hh0 = (const float*)d_in[4];
  const float* b0    = (const float*)d_in[5];
  const float* w_ihr = (const float*)d_in[6];
  const float* w_hhr = (const float*)d_in[7];
  const float* b_r   = (const float*)d_in[8];
  const int* bs_raw  = (const int*)d_in[9];
  const int* pidx    = (const int*)d_in[10];
  const int nrows = in_sizes[0] / 512;
  float* out = (float*)d_out;

  // Y0 (layer-0 output, f16, 67MB) aliases d_out's packed-out region (dead by l2).
  f16* Y0 = (f16*)d_out;
  float* hT = out + (size_t)nrows * 1024;
  float* cT = hT + (size_t)6 * NB * NH;

  char* p = (char*)d_ws;
  auto take = [&](size_t bytes) {
    char* r = p;
    p += (bytes + 255) & ~(size_t)255;
    return (void*)r;
  };
  f16* gxc   = (f16*)take((size_t)2 * CHUNK * NB * NG * 2);  // 67 MB
  f16* Y1    = (f16*)take((size_t)NT * NB * 1024 * 2);       // 67 MB
  f16* X0    = Y1;  // alias: X0 dead after l0 gemm; Y1 first written by l1 rec
  f16* wih16 = (f16*)take((size_t)2 * NG * 1024 * 2);
  f16* whh16 = (f16*)take((size_t)2 * NG * NH * 2);
  unsigned* ht = (unsigned*)take((size_t)2 * 2 * NB * NH * 4);  // tagged h, 512KB
  unsigned* ctr = (unsigned*)take((size_t)2 * 8 * 32 * 4);      // ready counters, 2KB
  float* hsave = (float*)take((size_t)2 * NB * NH * 4);
  float* csave = (float*)take((size_t)2 * NB * NH * 4);
  int* lens = (int*)take(256);
  int* cum  = (int*)take(NT * 4);

  prep_meta<<<1, 256, 0, stream>>>(bs_raw, lens, cum);
  (void)hipMemsetAsync(X0, 0, (size_t)NT * NB * 512 * 2, stream);
  (void)hipMemsetAsync(ht, 0, (size_t)2 * 2 * NB * NH * 4, stream);  // tags 0 (< any epoch)
  (void)hipMemsetAsync(ctr, 0, (size_t)2 * 8 * 32 * 4, stream);      // ctr 0 (< any epoch)
  scatter_rows<<<nrows, 256, 0, stream>>>(data, pidx, X0);

  for (int l = 0; l < 3; ++l) {
    const float* wih_f = (l == 0) ? w_ih0 : w_ihr + (size_t)(l - 1) * 2 * NG * 1024;
    const float* whh_f = (l == 0) ? w_hh0 : w_hhr + (size_t)(l - 1) * 2 * NG * NH;
    const float* bias  = (l == 0) ? b0 : b_r + (size_t)(l - 1) * 2 * NG;
    const int K = (l == 0) ? 512 : 1024;
    const f16* Xl = (l == 0) ? X0 : ((l == 1) ? Y0 : Y1);
    f16* Yl = (l == 0) ? Y0 : Y1;
    f32_to_f16<<<256, 256, 0, stream>>>(wih_f, wih16, (size_t)2 * NG * K);
    f32_to_f16<<<256, 256, 0, stream>>>(whh_f, whh16, (size_t)2 * NG * NH);
    init_h<<<256, 256, 0, stream>>>(h0, c0, hsave, csave, ht, ctr, l);
    for (int c = 0; c < 4; ++c) {
      gemm_gx<<<dim3(16, 64, 2), 256, 0, stream>>>(Xl, wih16, bias, lens, gxc, K, c * CHUNK);
      lstm_rec<<<64, 1024, 0, stream>>>(gxc, whh16, lens, cum, hsave, csave, ht, ctr, Yl,
                                        out, hT, cT, c * CHUNK, (l == 2) ? 1 : 0, l);
    }
  }
}

// Round 4
// 7055.882 us; speedup vs baseline: 1.2746x; 1.2746x over previous
//
#include <hip/hip_runtime.h>
#include <cmath>

typedef _Float16 f16;
typedef _Float16 half8 __attribute__((ext_vector_type(8)));
typedef float floatx4 __attribute__((ext_vector_type(4)));
typedef unsigned u32x4 __attribute__((ext_vector_type(4)));

#define NT 512
#define NB 64
#define NH 512
#define NG 2048
#define CHUNK 128

__device__ inline float sigf(float x) { return 1.0f / (1.0f + __expf(-x)); }
__device__ inline float tanhfast(float x) { return 2.0f / (1.0f + __expf(-2.0f * x)) - 1.0f; }

__device__ inline void load_lds16(const f16* g, f16* l) {
  __builtin_amdgcn_global_load_lds(
      (__attribute__((address_space(1))) void*)g,
      (__attribute__((address_space(3))) void*)l, 16, 0, 0);
}

// ---------------------------------------------------------------- meta
__global__ void prep_meta(const int* __restrict__ bs_raw, int* __restrict__ lens,
                          int* __restrict__ cum) {
  __shared__ int sbs[NT];
  int stride = (bs_raw[1] == 0) ? 2 : 1;  // int64 arrives as stride-2 int32
  for (int i = threadIdx.x; i < NT; i += 256) sbs[i] = bs_raw[i * stride];
  __syncthreads();
  for (int b = threadIdx.x; b < NB; b += 256) {
    int n = 0;
    for (int t = 0; t < NT; ++t) n += (sbs[t] > b);
    lens[b] = n;
  }
  if (threadIdx.x == 0) {
    int run = 0;
    for (int t = 0; t < NT; ++t) { cum[t] = run; run += sbs[t]; }
  }
}

// ---------------------------------------------------------------- unpack
__global__ void scatter_rows(const float* __restrict__ data, const int* __restrict__ pidx,
                             f16* __restrict__ X0) {
  int r = blockIdx.x;
  int row = pidx[r];
  const float* src = data + (size_t)r * 512;
  f16* dst = X0 + (size_t)row * 512;
  for (int k = threadIdx.x; k < 512; k += 256) dst[k] = (f16)src[k];
}

__global__ void f32_to_f16(const float* __restrict__ in, f16* __restrict__ out, size_t n) {
  size_t i = (size_t)blockIdx.x * 256 + threadIdx.x;
  size_t stride = (size_t)gridDim.x * 256;
  for (; i < n; i += stride) out[i] = (f16)in[i];
}

// ---------------------------------------------------------------- per-layer h/c init
// Writes tagged h words (epoch = layer*NT) into parity-0 and primes the
// parity-0 ready counters. Parity-1 leftovers from the previous layer are
// <= layer*NT, so they can never false-positive (epochs monotonic).
__global__ void init_h(const float* __restrict__ h0, const float* __restrict__ c0,
                       float* __restrict__ hsave, float* __restrict__ csave,
                       unsigned* __restrict__ ht, unsigned* __restrict__ ctr, int layer) {
  int idx = blockIdx.x * 256 + threadIdx.x;  // 2*64*512 = 65536
  int d = idx >> 15, rem = idx & 32767;
  float hv = h0[(size_t)(2 * layer + d) * NB * NH + rem];
  float cv = c0[(size_t)(2 * layer + d) * NB * NH + rem];
  hsave[idx] = hv;
  csave[idx] = cv;
  union { f16 f; unsigned short s; } hc; hc.f = (f16)hv;
  unsigned word = ((unsigned)(layer * NT) << 16) | hc.s;
  __hip_atomic_store(ht + (size_t)d * NB * NH + rem, word,
                     __ATOMIC_RELAXED, __HIP_MEMORY_SCOPE_AGENT);
  if (blockIdx.x == 0) {
    // parity-0 ready counters: slots [0][g][w] = 0..255
    __hip_atomic_store(ctr + threadIdx.x, (unsigned)(layer * NT),
                       __ATOMIC_RELAXED, __HIP_MEMORY_SCOPE_AGENT);
  }
}

// ---------------------------------------------------------------- gx GEMM (one chunk)
__global__ __launch_bounds__(256) void gemm_gx(const f16* __restrict__ A,
                                               const f16* __restrict__ W,
                                               const float* __restrict__ bias,
                                               const int* __restrict__ lens,
                                               f16* __restrict__ gxc, int K, int c0) {
  const int d = blockIdx.z;
  const int m0 = blockIdx.y * 128;
  const int n0 = blockIdx.x * 128;
  const f16* Wd = W + (size_t)d * NG * K;

  __shared__ __align__(16) f16 As[128 * 32];
  __shared__ __align__(16) f16 Bs[128 * 32];

  const int tid = threadIdx.x, lane = tid & 63, wv = tid >> 6;
  const int wm = wv >> 1, wn = wv & 1;
  const int lrow = lane >> 2, lcol = (lane & 3) * 8;
  const int q = lane >> 4, nn = lane & 15;

  const f16* aptr[2];
  const f16* bptr[2];
#pragma unroll
  for (int i = 0; i < 2; ++i) {
    int ch = wv * 2 + i;
    int m = m0 + ch * 16 + lrow;  // chunk-local row = ct*64 + b
    int t = c0 + (m >> 6), b = m & 63;
    int tt = t;
    if (d) { tt = lens[b] - 1 - t; tt = tt < 0 ? 0 : (tt > NT - 1 ? NT - 1 : tt); }
    aptr[i] = A + (size_t)(tt * NB + b) * K + lcol;
    bptr[i] = Wd + (size_t)(n0 + ch * 16 + lrow) * K + lcol;
  }

  floatx4 acc[4][4] = {};
  for (int k0 = 0; k0 < K; k0 += 32) {
    __syncthreads();
#pragma unroll
    for (int i = 0; i < 2; ++i) {
      int ch = wv * 2 + i;
      load_lds16(aptr[i] + k0, As + ch * 512);
      load_lds16(bptr[i] + k0, Bs + ch * 512);
    }
    __syncthreads();
    half8 a[4], b[4];
#pragma unroll
    for (int f = 0; f < 4; ++f) {
      a[f] = *(const half8*)(As + (wm * 64 + f * 16 + nn) * 32 + q * 8);
      b[f] = *(const half8*)(Bs + (wn * 64 + f * 16 + nn) * 32 + q * 8);
    }
#pragma unroll
    for (int fm = 0; fm < 4; ++fm)
#pragma unroll
      for (int fn = 0; fn < 4; ++fn)
        acc[fm][fn] = __builtin_amdgcn_mfma_f32_16x16x32_f16(a[fm], b[fn], acc[fm][fn], 0, 0, 0);
  }

  f16* gxd = gxc + (size_t)d * CHUNK * NB * NG;
#pragma unroll
  for (int fn = 0; fn < 4; ++fn) {
    int col = n0 + wn * 64 + fn * 16 + nn;
    float bv = bias[d * NG + col];
#pragma unroll
    for (int fm = 0; fm < 4; ++fm) {
      int mb = m0 + wm * 64 + fm * 16 + q * 4;
#pragma unroll
      for (int r = 0; r < 4; ++r)
        gxd[(size_t)(mb + r) * NG + col] = (f16)(acc[fm][fn][r] + bv);
    }
  }
}

// ---------------------------------------------------------------- recurrence (one chunk)
// 256 blocks = 8 groups x 32; group g = (dir=g&1, 16-row slice bsl=g>>1),
// closed under h dataflow. Sync = tagged-h words (epoch<<16 | f16 h),
// agent scope, pre-gated by per-producer ready counters ctr[par][g][w].
// The bump is deliberately RACY-EARLY (tid0, no drain): the consumer's
// tag-verify retries overlap the producer's store trickle (r3 proved the
// drained/barriered variant serializes and loses). Spin loops back off with
// s_sleep(1) after a failed check to stop the poll traffic from slowing the
// very stores being waited on. bf[] (whh fragments) are pinned in VGPRs via
// opaque asm -- without it the compiler remats the 16KB/wave load every step
// (r1 VGPR_Count=76 proves bf was not resident).
__global__ __launch_bounds__(256, 1) void lstm_rec(
    const f16* __restrict__ gxc, const f16* __restrict__ whh,
    const int* __restrict__ lens, const int* __restrict__ cum,
    float* __restrict__ hsave, float* __restrict__ csave,
    unsigned* __restrict__ ht, unsigned* __restrict__ ctr,
    f16* __restrict__ Y, float* __restrict__ outp,
    float* __restrict__ hT, float* __restrict__ cT,
    int c0, int mode, int layer) {
  const int tid = threadIdx.x, lane = tid & 63, wv = tid >> 6;
  const int g = blockIdx.x & 7, w = blockIdx.x >> 3;
  const int dir = g & 1, bsl = g >> 1;
  const int q = lane >> 4, nn = lane & 15;

  const int maxlen = lens[bsl * 16];  // rows sorted desc: uniform group exit
  int nst = maxlen - c0;
  if (nst <= 0) return;
  if (nst > CHUNK) nst = CHUNK;

  // LDS: double-buffered extracted-A tile (16 rows x 512 k f16, packed u32)
  __shared__ __align__(16) unsigned As[2][16][260];
  __shared__ float s_g[4][16][17];

  const int jbase = w * 16 + wv * 4;
  const int coln = (nn >> 2) * NH + jbase + (nn & 3);
  const f16* whd = whh + (size_t)dir * NG * NH;
  half8 bf[16];
#pragma unroll
  for (int s = 0; s < 16; ++s) {
    bf[s] = *(const half8*)(whd + (size_t)coln * NH + s * 32 + q * 8);
    asm volatile("" : "+v"(bf[s]));  // opaque def: force VGPR residency across the loop
  }

  const int b_e = bsl * 16 + nn;
  const int jglob = jbase + q;
  const int lene = lens[b_e];
  const int brow = bsl * 16 + q * 4;
  const int lidx = (dir * NB + b_e) * NH + jglob;
  float h = hsave[lidx], c = csave[lidx];

  const f16* gxd = gxc + (size_t)dir * CHUNK * NB * NG;
  const int ebase = layer * NT;  // epochs monotonic across chunks & layers

  const unsigned* cslot = ctr + (size_t)g * 32 + (lane & 31);

  for (int ct = 0; ct < nst; ++ct) {
    const int t = c0 + ct;
    const int e = ebase + t;      // tag required on consumed h
    const int par = t & 1;

    // gx loads issued early (HBM latency overlaps the wait)
    float gxv[4];
#pragma unroll
    for (int r = 0; r < 4; ++r)
      gxv[r] = (float)gxd[(size_t)(ct * NB + brow + r) * NG + coln];

    // ---- cheap readiness gate: 1 coalesced line/wave/iteration ----
    {
      const unsigned* cp = cslot + par * 256;
      int it = 0;
      for (;;) {
        unsigned cv = __hip_atomic_load(cp, __ATOMIC_RELAXED, __HIP_MEMORY_SCOPE_AGENT);
        if (__ballot((int)cv >= e) == ~0ull) break;
        if (++it > 200000) break;  // fail as wrong-answer, not hang
        __builtin_amdgcn_s_sleep(1);  // 64cy backoff: cut MALL poll contention
      }
    }

    // ---- flat data pass, tag-verified (full MLP: 16 u64 in flight) ----
    // lane (q,nn): row nn, words k = wv*128 + s*32 + q*8 .. +8
    const unsigned long long* p64 =
        (const unsigned long long*)(ht + ((size_t)(par * 2 + dir) * NB + bsl * 16 + nn) * NH +
                                    wv * 128 + q * 8);
    unsigned long long wb[16];
    {
      int it = 0;
      for (;;) {
#pragma unroll
        for (int i = 0; i < 16; ++i)
          wb[i] = __hip_atomic_load(p64 + (i >> 2) * 16 + (i & 3), __ATOMIC_RELAXED,
                                    __HIP_MEMORY_SCOPE_AGENT);
        unsigned tg = 0xffffu;
#pragma unroll
        for (int i = 0; i < 16; ++i) {
          tg &= (unsigned)(wb[i] >> 16) & 0xffffu;
          tg &= (unsigned)(wb[i] >> 48);
        }
        // words hold only epoch e or e-2 (ping-pong parity); AND(e-2, e) < e,
        // AND(all e) == e -> exact freshness test.
        if (__ballot(tg >= (unsigned)e) == ~0ull) break;
        if (++it > 50000) break;  // fail as wrong-answer, not hang
        __builtin_amdgcn_s_sleep(1);
      }
    }

    // ---- extract f16 payloads -> LDS A tile ----
#pragma unroll
    for (int s = 0; s < 4; ++s) {
      unsigned d0 = (unsigned)(wb[4 * s + 0] & 0xffffu) | ((unsigned)(wb[4 * s + 0] >> 32) << 16);
      unsigned d1 = (unsigned)(wb[4 * s + 1] & 0xffffu) | ((unsigned)(wb[4 * s + 1] >> 32) << 16);
      unsigned d2 = (unsigned)(wb[4 * s + 2] & 0xffffu) | ((unsigned)(wb[4 * s + 2] >> 32) << 16);
      unsigned d3 = (unsigned)(wb[4 * s + 3] & 0xffffu) | ((unsigned)(wb[4 * s + 3] >> 32) << 16);
      *(u32x4*)&As[par][nn][wv * 64 + s * 16 + q * 4] = (u32x4){d0, d1, d2, d3};
    }
    __syncthreads();  // the ONLY per-step barrier (block-local)

    // ---- MFMA: 16 k-slabs from LDS ----
    floatx4 acc0 = {0.f, 0.f, 0.f, 0.f}, acc1 = {0.f, 0.f, 0.f, 0.f};
#pragma unroll
    for (int s = 0; s < 8; ++s) {
      half8 a0 = *(const half8*)&As[par][nn][(2 * s) * 16 + q * 4];
      half8 a1 = *(const half8*)&As[par][nn][(2 * s + 1) * 16 + q * 4];
      acc0 = __builtin_amdgcn_mfma_f32_16x16x32_f16(a0, bf[2 * s], acc0, 0, 0, 0);
      acc1 = __builtin_amdgcn_mfma_f32_16x16x32_f16(a1, bf[2 * s + 1], acc1, 0, 0, 0);
    }
#pragma unroll
    for (int r4 = 0; r4 < 4; ++r4) s_g[wv][q * 4 + r4][nn] = acc0[r4] + acc1[r4] + gxv[r4];
    // s_g[wv] is wave-private: ds ordering (lgkmcnt) suffices, no barrier.

    const bool act = (t < lene);
    if (act) {
      float gi = s_g[wv][nn][q];
      float gf = s_g[wv][nn][4 + q];
      float gg = s_g[wv][nn][8 + q];
      float go = s_g[wv][nn][12 + q];
      c = sigf(gf) * c + sigf(gi) * tanhfast(gg);
      h = sigf(go) * tanhfast(c);
    }
    // ---- tagged publish (the sync) ----
    union { f16 f; unsigned short s; } hc; hc.f = (f16)h;
    unsigned word = ((unsigned)(e + 1) << 16) | hc.s;
    __hip_atomic_store(ht + ((size_t)(((t + 1) & 1) * 2 + dir) * NB + b_e) * NH + jglob,
                       word, __ATOMIC_RELAXED, __HIP_MEMORY_SCOPE_AGENT);
    // ready-counter bump: racy-early HINT (tags remain the proof)
    if (tid == 0)
      __hip_atomic_store(ctr + (size_t)(((t + 1) & 1) * 256 + g * 32 + w), (unsigned)(e + 1),
                         __ATOMIC_RELAXED, __HIP_MEMORY_SCOPE_AGENT);
    // Y / packed-out stores: fire-and-forget, drain under later waits
    if (mode == 0) {
      int tp = act ? (dir ? (lene - 1 - t) : t) : t;
      Y[(size_t)(tp * NB + b_e) * (2 * NH) + dir * NH + jglob] = act ? (f16)h : (f16)0.f;
    } else if (act) {
      int tp = dir ? (lene - 1 - t) : t;
      outp[(size_t)(cum[tp] + b_e) * (2 * NH) + dir * NH + jglob] = h;
    }
  }

  hsave[lidx] = h;
  csave[lidx] = c;
  const int sidx = ((2 * layer + dir) * NB + b_e) * NH + jglob;
  hT[sidx] = h;
  cT[sidx] = c;
}

// ---------------------------------------------------------------- host
extern "C" void kernel_launch(void* const* d_in, const int* in_sizes, int n_in,
                              void* d_out, int out_size, void* d_ws, size_t ws_size,
                              hipStream_t stream) {
  const float* data  = (const float*)d_in[0];
  const float* h0    = (const float*)d_in[1];
  const float* c0    = (const float*)d_in[2];
  const float* w_ih0 = (const float*)d_in[3];
  const float* w_hh0 = (const float*)d_in[4];
  const float* b0    = (const float*)d_in[5];
  const float* w_ihr = (const float*)d_in[6];
  const float* w_hhr = (const float*)d_in[7];
  const float* b_r   = (const float*)d_in[8];
  const int* bs_raw  = (const int*)d_in[9];
  const int* pidx    = (const int*)d_in[10];
  const int nrows = in_sizes[0] / 512;
  float* out = (float*)d_out;

  // Y0 (layer-0 output, f16, 67MB) aliases d_out's packed-out region (dead by l2).
  f16* Y0 = (f16*)d_out;
  float* hT = out + (size_t)nrows * 1024;
  float* cT = hT + (size_t)6 * NB * NH;

  char* p = (char*)d_ws;
  auto take = [&](size_t bytes) {
    char* r = p;
    p += (bytes + 255) & ~(size_t)255;
    return (void*)r;
  };
  f16* gxc   = (f16*)take((size_t)2 * CHUNK * NB * NG * 2);  // 67 MB
  f16* Y1    = (f16*)take((size_t)NT * NB * 1024 * 2);       // 67 MB
  f16* X0    = Y1;  // alias: X0 dead after l0 gemm; Y1 first written by l1 rec
  f16* wih16 = (f16*)take((size_t)2 * NG * 1024 * 2);
  f16* whh16 = (f16*)take((size_t)2 * NG * NH * 2);
  unsigned* ht = (unsigned*)take((size_t)2 * 2 * NB * NH * 4);  // tagged h, 512KB
  unsigned* ctr = (unsigned*)take((size_t)2 * 8 * 32 * 4);      // ready counters, 2KB
  float* hsave = (float*)take((size_t)2 * NB * NH * 4);
  float* csave = (float*)take((size_t)2 * NB * NH * 4);
  int* lens = (int*)take(256);
  int* cum  = (int*)take(NT * 4);

  prep_meta<<<1, 256, 0, stream>>>(bs_raw, lens, cum);
  (void)hipMemsetAsync(X0, 0, (size_t)NT * NB * 512 * 2, stream);
  (void)hipMemsetAsync(ht, 0, (size_t)2 * 2 * NB * NH * 4, stream);  // tags 0 (< any epoch)
  (void)hipMemsetAsync(ctr, 0, (size_t)2 * 8 * 32 * 4, stream);      // ctr 0 (< any epoch)
  scatter_rows<<<nrows, 256, 0, stream>>>(data, pidx, X0);

  for (int l = 0; l < 3; ++l) {
    const float* wih_f = (l == 0) ? w_ih0 : w_ihr + (size_t)(l - 1) * 2 * NG * 1024;
    const float* whh_f = (l == 0) ? w_hh0 : w_hhr + (size_t)(l - 1) * 2 * NG * NH;
    const float* bias  = (l == 0) ? b0 : b_r + (size_t)(l - 1) * 2 * NG;
    const int K = (l == 0) ? 512 : 1024;
    const f16* Xl = (l == 0) ? X0 : ((l == 1) ? Y0 : Y1);
    f16* Yl = (l == 0) ? Y0 : Y1;
    f32_to_f16<<<256, 256, 0, stream>>>(wih_f, wih16, (size_t)2 * NG * K);
    f32_to_f16<<<256, 256, 0, stream>>>(whh_f, whh16, (size_t)2 * NG * NH);
    init_h<<<256, 256, 0, stream>>>(h0, c0, hsave, csave, ht, ctr, l);
    for (int c = 0; c < 4; ++c) {
      gemm_gx<<<dim3(16, 64, 2), 256, 0, stream>>>(Xl, wih16, bias, lens, gxc, K, c * CHUNK);
      lstm_rec<<<256, 256, 0, stream>>>(gxc, whh16, lens, cum, hsave, csave, ht, ctr, Yl,
                                        out, hT, cT, c * CHUNK, (l == 2) ? 1 : 0, l);
    }
  }
}

// Round 5
// 6990.342 us; speedup vs baseline: 1.2866x; 1.0094x over previous
//
#include <hip/hip_runtime.h>
#include <cmath>

typedef _Float16 f16;
typedef _Float16 half8 __attribute__((ext_vector_type(8)));
typedef float floatx4 __attribute__((ext_vector_type(4)));
typedef unsigned u32x4 __attribute__((ext_vector_type(4)));

#define NT 512
#define NB 64
#define NH 512
#define NG 2048
#define CHUNK 128

__device__ inline float sigf(float x) { return 1.0f / (1.0f + __expf(-x)); }
__device__ inline float tanhfast(float x) { return 2.0f / (1.0f + __expf(-2.0f * x)) - 1.0f; }

__device__ inline void load_lds16(const f16* g, f16* l) {
  __builtin_amdgcn_global_load_lds(
      (__attribute__((address_space(1))) void*)g,
      (__attribute__((address_space(3))) void*)l, 16, 0, 0);
}

// ---------------------------------------------------------------- meta
__global__ void prep_meta(const int* __restrict__ bs_raw, int* __restrict__ lens,
                          int* __restrict__ cum) {
  __shared__ int sbs[NT];
  int stride = (bs_raw[1] == 0) ? 2 : 1;  // int64 arrives as stride-2 int32
  for (int i = threadIdx.x; i < NT; i += 256) sbs[i] = bs_raw[i * stride];
  __syncthreads();
  for (int b = threadIdx.x; b < NB; b += 256) {
    int n = 0;
    for (int t = 0; t < NT; ++t) n += (sbs[t] > b);
    lens[b] = n;
  }
  if (threadIdx.x == 0) {
    int run = 0;
    for (int t = 0; t < NT; ++t) { cum[t] = run; run += sbs[t]; }
  }
}

// ---------------------------------------------------------------- unpack
__global__ void scatter_rows(const float* __restrict__ data, const int* __restrict__ pidx,
                             f16* __restrict__ X0) {
  int r = blockIdx.x;
  int row = pidx[r];
  const float* src = data + (size_t)r * 512;
  f16* dst = X0 + (size_t)row * 512;
  for (int k = threadIdx.x; k < 512; k += 256) dst[k] = (f16)src[k];
}

__global__ void f32_to_f16(const float* __restrict__ in, f16* __restrict__ out, size_t n) {
  size_t i = (size_t)blockIdx.x * 256 + threadIdx.x;
  size_t stride = (size_t)gridDim.x * 256;
  for (; i < n; i += stride) out[i] = (f16)in[i];
}

// ---------------------------------------------------------------- per-layer h/c init
// Writes tagged h words (epoch = layer*NT) into parity-0 and primes the
// parity-0 ready counters. Parity-1 leftovers from the previous layer are
// <= layer*NT, so they can never false-positive (epochs monotonic).
__global__ void init_h(const float* __restrict__ h0, const float* __restrict__ c0,
                       float* __restrict__ hsave, float* __restrict__ csave,
                       unsigned* __restrict__ ht, unsigned* __restrict__ ctr, int layer) {
  int idx = blockIdx.x * 256 + threadIdx.x;  // 2*64*512 = 65536
  int d = idx >> 15, rem = idx & 32767;
  float hv = h0[(size_t)(2 * layer + d) * NB * NH + rem];
  float cv = c0[(size_t)(2 * layer + d) * NB * NH + rem];
  hsave[idx] = hv;
  csave[idx] = cv;
  union { f16 f; unsigned short s; } hc; hc.f = (f16)hv;
  unsigned word = ((unsigned)(layer * NT) << 16) | hc.s;
  __hip_atomic_store(ht + (size_t)d * NB * NH + rem, word,
                     __ATOMIC_RELAXED, __HIP_MEMORY_SCOPE_AGENT);
  if (blockIdx.x == 0) {
    // parity-0 ready counters: slots [0][g][w] = 0..255
    __hip_atomic_store(ctr + threadIdx.x, (unsigned)(layer * NT),
                       __ATOMIC_RELAXED, __HIP_MEMORY_SCOPE_AGENT);
  }
}

// ---------------------------------------------------------------- gx GEMM body
// id = d*1024 + my*16 + nx  (d: dir, my: 128-row m-tile, nx: 128-col n-tile)
__device__ void gemm_body(const f16* __restrict__ A, const f16* __restrict__ W,
                          const float* __restrict__ bias, const int* __restrict__ lens,
                          f16* __restrict__ gxc, int K, int c0, int id) {
  const int d = id >> 10;
  const int m0 = ((id >> 4) & 63) * 128;
  const int n0 = (id & 15) * 128;
  const f16* Wd = W + (size_t)d * NG * K;

  __shared__ __align__(16) f16 As[128 * 32];
  __shared__ __align__(16) f16 Bs[128 * 32];

  const int tid = threadIdx.x, lane = tid & 63, wv = tid >> 6;
  const int wm = wv >> 1, wn = wv & 1;
  const int lrow = lane >> 2, lcol = (lane & 3) * 8;
  const int q = lane >> 4, nn = lane & 15;

  const f16* aptr[2];
  const f16* bptr[2];
#pragma unroll
  for (int i = 0; i < 2; ++i) {
    int ch = wv * 2 + i;
    int m = m0 + ch * 16 + lrow;  // chunk-local row = ct*64 + b
    int t = c0 + (m >> 6), b = m & 63;
    int tt = t;
    if (d) { tt = lens[b] - 1 - t; tt = tt < 0 ? 0 : (tt > NT - 1 ? NT - 1 : tt); }
    aptr[i] = A + (size_t)(tt * NB + b) * K + lcol;
    bptr[i] = Wd + (size_t)(n0 + ch * 16 + lrow) * K + lcol;
  }

  floatx4 acc[4][4] = {};
  for (int k0 = 0; k0 < K; k0 += 32) {
    __syncthreads();
#pragma unroll
    for (int i = 0; i < 2; ++i) {
      int ch = wv * 2 + i;
      load_lds16(aptr[i] + k0, As + ch * 512);
      load_lds16(bptr[i] + k0, Bs + ch * 512);
    }
    __syncthreads();
    half8 a[4], b[4];
#pragma unroll
    for (int f = 0; f < 4; ++f) {
      a[f] = *(const half8*)(As + (wm * 64 + f * 16 + nn) * 32 + q * 8);
      b[f] = *(const half8*)(Bs + (wn * 64 + f * 16 + nn) * 32 + q * 8);
    }
#pragma unroll
    for (int fm = 0; fm < 4; ++fm)
#pragma unroll
      for (int fn = 0; fn < 4; ++fn)
        acc[fm][fn] = __builtin_amdgcn_mfma_f32_16x16x32_f16(a[fm], b[fn], acc[fm][fn], 0, 0, 0);
  }

  f16* gxd = gxc + (size_t)d * CHUNK * NB * NG;
#pragma unroll
  for (int fn = 0; fn < 4; ++fn) {
    int col = n0 + wn * 64 + fn * 16 + nn;
    float bv = bias[d * NG + col];
#pragma unroll
    for (int fm = 0; fm < 4; ++fm) {
      int mb = m0 + wm * 64 + fm * 16 + q * 4;
#pragma unroll
      for (int r = 0; r < 4; ++r)
        gxd[(size_t)(mb + r) * NG + col] = (f16)(acc[fm][fn][r] + bv);
    }
  }
}

__global__ __launch_bounds__(256) void gemm_gx(const f16* __restrict__ A,
                                               const f16* __restrict__ W,
                                               const float* __restrict__ bias,
                                               const int* __restrict__ lens,
                                               f16* __restrict__ gxc, int K, int c0) {
  gemm_body(A, W, bias, lens, gxc, K, c0,
            (int)(blockIdx.z * 1024 + blockIdx.y * 16 + blockIdx.x));
}

// ---------------------------------------------------------------- recurrence (one chunk)
// HYBRID GRID: blocks 0..255 = rec role (r4's verified free-running tagged
// protocol, unchanged); blocks 256..2303 = gemm role computing the NEXT
// chunk's gx into the ping-pong buffer (fully independent of rec; dispatch
// boundary provides visibility for the next rec dispatch). Rec blocks have
// the low IDs so they dispatch first -> co-residency preserved; gemm blocks
// fill the CUs' remaining slots and run in the rec blocks' idle-wait shadow.
__global__ __launch_bounds__(256, 1) void lstm_rec(
    const f16* __restrict__ gxc, const f16* __restrict__ whh,
    const int* __restrict__ lens, const int* __restrict__ cum,
    float* __restrict__ hsave, float* __restrict__ csave,
    unsigned* __restrict__ ht, unsigned* __restrict__ ctr,
    f16* __restrict__ Y, float* __restrict__ outp,
    float* __restrict__ hT, float* __restrict__ cT,
    int c0, int mode, int layer,
    const f16* __restrict__ Xg, const f16* __restrict__ wih,
    const float* __restrict__ biasg, f16* __restrict__ gxn, int Kg, int c0n) {
  if (blockIdx.x >= 256) {
    if (gxn) gemm_body(Xg, wih, biasg, lens, gxn, Kg, c0n, (int)blockIdx.x - 256);
    return;
  }
  const int tid = threadIdx.x, lane = tid & 63, wv = tid >> 6;
  const int g = blockIdx.x & 7, w = blockIdx.x >> 3;
  const int dir = g & 1, bsl = g >> 1;
  const int q = lane >> 4, nn = lane & 15;

  const int maxlen = lens[bsl * 16];  // rows sorted desc: uniform group exit
  int nst = maxlen - c0;
  if (nst <= 0) return;
  if (nst > CHUNK) nst = CHUNK;

  // LDS: double-buffered extracted-A tile (16 rows x 512 k f16, packed u32)
  __shared__ __align__(16) unsigned As[2][16][260];
  __shared__ float s_g[4][16][17];

  const int jbase = w * 16 + wv * 4;
  const int coln = (nn >> 2) * NH + jbase + (nn & 3);
  const f16* whd = whh + (size_t)dir * NG * NH;
  half8 bf[16];
#pragma unroll
  for (int s = 0; s < 16; ++s) {
    bf[s] = *(const half8*)(whd + (size_t)coln * NH + s * 32 + q * 8);
    asm volatile("" : "+v"(bf[s]));  // opaque def: discourage remat
  }

  const int b_e = bsl * 16 + nn;
  const int jglob = jbase + q;
  const int lene = lens[b_e];
  const int brow = bsl * 16 + q * 4;
  const int lidx = (dir * NB + b_e) * NH + jglob;
  float h = hsave[lidx], c = csave[lidx];

  const f16* gxd = gxc + (size_t)dir * CHUNK * NB * NG;
  const int ebase = layer * NT;  // epochs monotonic across chunks & layers

  const unsigned* cslot = ctr + (size_t)g * 32 + (lane & 31);

  for (int ct = 0; ct < nst; ++ct) {
    const int t = c0 + ct;
    const int e = ebase + t;      // tag required on consumed h
    const int par = t & 1;

    // gx loads issued early (HBM latency overlaps the wait)
    float gxv[4];
#pragma unroll
    for (int r = 0; r < 4; ++r)
      gxv[r] = (float)gxd[(size_t)(ct * NB + brow + r) * NG + coln];

    // ---- cheap readiness gate: 1 coalesced line/wave/iteration ----
    {
      const unsigned* cp = cslot + par * 256;
      int it = 0;
      for (;;) {
        unsigned cv = __hip_atomic_load(cp, __ATOMIC_RELAXED, __HIP_MEMORY_SCOPE_AGENT);
        if (__ballot((int)cv >= e) == ~0ull) break;
        if (++it > 200000) break;  // fail as wrong-answer, not hang
        __builtin_amdgcn_s_sleep(1);  // 64cy backoff: cut MALL poll contention
      }
    }

    // ---- flat data pass, tag-verified (full MLP: 16 u64 in flight) ----
    // lane (q,nn): row nn, words k = wv*128 + s*32 + q*8 .. +8
    const unsigned long long* p64 =
        (const unsigned long long*)(ht + ((size_t)(par * 2 + dir) * NB + bsl * 16 + nn) * NH +
                                    wv * 128 + q * 8);
    unsigned long long wb[16];
    {
      int it = 0;
      for (;;) {
#pragma unroll
        for (int i = 0; i < 16; ++i)
          wb[i] = __hip_atomic_load(p64 + (i >> 2) * 16 + (i & 3), __ATOMIC_RELAXED,
                                    __HIP_MEMORY_SCOPE_AGENT);
        unsigned tg = 0xffffu;
#pragma unroll
        for (int i = 0; i < 16; ++i) {
          tg &= (unsigned)(wb[i] >> 16) & 0xffffu;
          tg &= (unsigned)(wb[i] >> 48);
        }
        // words hold only epoch e or e-2 (ping-pong parity); AND(e-2, e) < e,
        // AND(all e) == e -> exact freshness test.
        if (__ballot(tg >= (unsigned)e) == ~0ull) break;
        if (++it > 50000) break;  // fail as wrong-answer, not hang
        __builtin_amdgcn_s_sleep(1);
      }
    }

    // ---- extract f16 payloads -> LDS A tile ----
#pragma unroll
    for (int s = 0; s < 4; ++s) {
      unsigned d0 = (unsigned)(wb[4 * s + 0] & 0xffffu) | ((unsigned)(wb[4 * s + 0] >> 32) << 16);
      unsigned d1 = (unsigned)(wb[4 * s + 1] & 0xffffu) | ((unsigned)(wb[4 * s + 1] >> 32) << 16);
      unsigned d2 = (unsigned)(wb[4 * s + 2] & 0xffffu) | ((unsigned)(wb[4 * s + 2] >> 32) << 16);
      unsigned d3 = (unsigned)(wb[4 * s + 3] & 0xffffu) | ((unsigned)(wb[4 * s + 3] >> 32) << 16);
      *(u32x4*)&As[par][nn][wv * 64 + s * 16 + q * 4] = (u32x4){d0, d1, d2, d3};
    }
    __syncthreads();  // the ONLY per-step barrier (block-local)

    // ---- MFMA: 16 k-slabs from LDS ----
    floatx4 acc0 = {0.f, 0.f, 0.f, 0.f}, acc1 = {0.f, 0.f, 0.f, 0.f};
#pragma unroll
    for (int s = 0; s < 8; ++s) {
      half8 a0 = *(const half8*)&As[par][nn][(2 * s) * 16 + q * 4];
      half8 a1 = *(const half8*)&As[par][nn][(2 * s + 1) * 16 + q * 4];
      acc0 = __builtin_amdgcn_mfma_f32_16x16x32_f16(a0, bf[2 * s], acc0, 0, 0, 0);
      acc1 = __builtin_amdgcn_mfma_f32_16x16x32_f16(a1, bf[2 * s + 1], acc1, 0, 0, 0);
    }
#pragma unroll
    for (int r4 = 0; r4 < 4; ++r4) s_g[wv][q * 4 + r4][nn] = acc0[r4] + acc1[r4] + gxv[r4];
    // s_g[wv] is wave-private: ds ordering (lgkmcnt) suffices, no barrier.

    const bool act = (t < lene);
    if (act) {
      float gi = s_g[wv][nn][q];
      float gf = s_g[wv][nn][4 + q];
      float gg = s_g[wv][nn][8 + q];
      float go = s_g[wv][nn][12 + q];
      c = sigf(gf) * c + sigf(gi) * tanhfast(gg);
      h = sigf(go) * tanhfast(c);
    }
    // ---- tagged publish (the sync) ----
    union { f16 f; unsigned short s; } hc; hc.f = (f16)h;
    unsigned word = ((unsigned)(e + 1) << 16) | hc.s;
    __hip_atomic_store(ht + ((size_t)(((t + 1) & 1) * 2 + dir) * NB + b_e) * NH + jglob,
                       word, __ATOMIC_RELAXED, __HIP_MEMORY_SCOPE_AGENT);
    // ready-counter bump: racy-early HINT (tags remain the proof)
    if (tid == 0)
      __hip_atomic_store(ctr + (size_t)(((t + 1) & 1) * 256 + g * 32 + w), (unsigned)(e + 1),
                         __ATOMIC_RELAXED, __HIP_MEMORY_SCOPE_AGENT);
    // Y / packed-out stores: fire-and-forget, drain under later waits
    if (mode == 0) {
      int tp = act ? (dir ? (lene - 1 - t) : t) : t;
      Y[(size_t)(tp * NB + b_e) * (2 * NH) + dir * NH + jglob] = act ? (f16)h : (f16)0.f;
    } else if (act) {
      int tp = dir ? (lene - 1 - t) : t;
      outp[(size_t)(cum[tp] + b_e) * (2 * NH) + dir * NH + jglob] = h;
    }
  }

  hsave[lidx] = h;
  csave[lidx] = c;
  const int sidx = ((2 * layer + dir) * NB + b_e) * NH + jglob;
  hT[sidx] = h;
  cT[sidx] = c;
}

// ---------------------------------------------------------------- host
extern "C" void kernel_launch(void* const* d_in, const int* in_sizes, int n_in,
                              void* d_out, int out_size, void* d_ws, size_t ws_size,
                              hipStream_t stream) {
  const float* data  = (const float*)d_in[0];
  const float* h0    = (const float*)d_in[1];
  const float* c0    = (const float*)d_in[2];
  const float* w_ih0 = (const float*)d_in[3];
  const float* w_hh0 = (const float*)d_in[4];
  const float* b0    = (const float*)d_in[5];
  const float* w_ihr = (const float*)d_in[6];
  const float* w_hhr = (const float*)d_in[7];
  const float* b_r   = (const float*)d_in[8];
  const int* bs_raw  = (const int*)d_in[9];
  const int* pidx    = (const int*)d_in[10];
  const int nrows = in_sizes[0] / 512;
  float* out = (float*)d_out;

  // Y0 (layer-0 output, f16, 67MB) aliases d_out's packed-out region (dead by l2).
  f16* Y0 = (f16*)d_out;
  float* hT = out + (size_t)nrows * 1024;
  float* cT = hT + (size_t)6 * NB * NH;

  char* p = (char*)d_ws;
  auto take = [&](size_t bytes) {
    char* r = p;
    p += (bytes + 255) & ~(size_t)255;
    return (void*)r;
  };
  const size_t gsz = (size_t)2 * CHUNK * NB * NG * 2;        // 67 MB per gx buffer
  f16* gxcA  = (f16*)take(gsz);
  f16* Y1    = (f16*)take((size_t)NT * NB * 1024 * 2);       // 67 MB
  f16* X0    = Y1;  // alias: X0 dead after l0 gemm; Y1 first written by l1 rec
  f16* wih16 = (f16*)take((size_t)2 * NG * 1024 * 2);
  f16* whh16 = (f16*)take((size_t)2 * NG * NH * 2);
  unsigned* ht = (unsigned*)take((size_t)2 * 2 * NB * NH * 4);  // tagged h, 512KB
  unsigned* ctr = (unsigned*)take((size_t)2 * 8 * 32 * 4);      // ready counters, 2KB
  float* hsave = (float*)take((size_t)2 * NB * NH * 4);
  float* csave = (float*)take((size_t)2 * NB * NH * 4);
  int* lens = (int*)take(256);
  int* cum  = (int*)take(NT * 4);
  // second gx buffer (ping-pong for fused next-chunk gemm) -- only if it fits
  f16* gxcB = nullptr;
  if ((size_t)(p - (char*)d_ws) + gsz <= ws_size) gxcB = (f16*)take(gsz);
  const bool fuse = (gxcB != nullptr);

  prep_meta<<<1, 256, 0, stream>>>(bs_raw, lens, cum);
  (void)hipMemsetAsync(X0, 0, (size_t)NT * NB * 512 * 2, stream);
  (void)hipMemsetAsync(ht, 0, (size_t)2 * 2 * NB * NH * 4, stream);  // tags 0 (< any epoch)
  (void)hipMemsetAsync(ctr, 0, (size_t)2 * 8 * 32 * 4, stream);      // ctr 0 (< any epoch)
  scatter_rows<<<nrows, 256, 0, stream>>>(data, pidx, X0);

  for (int l = 0; l < 3; ++l) {
    const float* wih_f = (l == 0) ? w_ih0 : w_ihr + (size_t)(l - 1) * 2 * NG * 1024;
    const float* whh_f = (l == 0) ? w_hh0 : w_hhr + (size_t)(l - 1) * 2 * NG * NH;
    const float* bias  = (l == 0) ? b0 : b_r + (size_t)(l - 1) * 2 * NG;
    const int K = (l == 0) ? 512 : 1024;
    const f16* Xl = (l == 0) ? X0 : ((l == 1) ? Y0 : Y1);
    f16* Yl = (l == 0) ? Y0 : Y1;
    f32_to_f16<<<256, 256, 0, stream>>>(wih_f, wih16, (size_t)2 * NG * K);
    f32_to_f16<<<256, 256, 0, stream>>>(whh_f, whh16, (size_t)2 * NG * NH);
    init_h<<<256, 256, 0, stream>>>(h0, c0, hsave, csave, ht, ctr, l);
    for (int c = 0; c < 4; ++c) {
      f16* gcur = fuse ? ((c & 1) ? gxcB : gxcA) : gxcA;
      if (c == 0 || !fuse)
        gemm_gx<<<dim3(16, 64, 2), 256, 0, stream>>>(Xl, wih16, bias, lens, gcur, K, c * CHUNK);
      const bool g_on = fuse && (c < 3);
      f16* gnext = g_on ? (((c + 1) & 1) ? gxcB : gxcA) : nullptr;
      const int grid = g_on ? 2304 : 256;
      lstm_rec<<<grid, 256, 0, stream>>>(gcur, whh16, lens, cum, hsave, csave, ht, ctr, Yl,
                                         out, hT, cT, c * CHUNK, (l == 2) ? 1 : 0, l,
                                         Xl, wih16, bias, gnext, K, (c + 1) * CHUNK);
    }
  }
}

// Round 6
// 6826.350 us; speedup vs baseline: 1.3175x; 1.0240x over previous
//
#include <hip/hip_runtime.h>
#include <cmath>

typedef _Float16 f16;
typedef _Float16 half8 __attribute__((ext_vector_type(8)));
typedef float floatx4 __attribute__((ext_vector_type(4)));
typedef unsigned u32x4 __attribute__((ext_vector_type(4)));

#define NT 512
#define NB 64
#define NH 512
#define NG 2048
#define CHUNK 128

__device__ inline float sigf(float x) { return 1.0f / (1.0f + __expf(-x)); }
__device__ inline float tanhfast(float x) { return 2.0f / (1.0f + __expf(-2.0f * x)) - 1.0f; }

__device__ inline void load_lds16(const f16* g, f16* l) {
  __builtin_amdgcn_global_load_lds(
      (__attribute__((address_space(1))) void*)g,
      (__attribute__((address_space(3))) void*)l, 16, 0, 0);
}

// ---------------------------------------------------------------- meta
__global__ void prep_meta(const int* __restrict__ bs_raw, int* __restrict__ lens,
                          int* __restrict__ cum) {
  __shared__ int sbs[NT];
  int stride = (bs_raw[1] == 0) ? 2 : 1;  // int64 arrives as stride-2 int32
  for (int i = threadIdx.x; i < NT; i += 256) sbs[i] = bs_raw[i * stride];
  __syncthreads();
  for (int b = threadIdx.x; b < NB; b += 256) {
    int n = 0;
    for (int t = 0; t < NT; ++t) n += (sbs[t] > b);
    lens[b] = n;
  }
  if (threadIdx.x == 0) {
    int run = 0;
    for (int t = 0; t < NT; ++t) { cum[t] = run; run += sbs[t]; }
  }
}

// ---------------------------------------------------------------- unpack
__global__ void scatter_rows(const float* __restrict__ data, const int* __restrict__ pidx,
                             f16* __restrict__ X0) {
  int r = blockIdx.x;
  int row = pidx[r];
  const float* src = data + (size_t)r * 512;
  f16* dst = X0 + (size_t)row * 512;
  for (int k = threadIdx.x; k < 512; k += 256) dst[k] = (f16)src[k];
}

// ---------------------------------------------------------------- per-layer prep
// Fuses: wih f32->f16, whh f32->f16, h/c init + tagged parity-0 publish +
// parity-0 ready-counter priming (epoch = layer*NT; monotonic across layers,
// so stale parity-1 leftovers can never false-positive).
__global__ void prep_layer(const float* __restrict__ wih_f, f16* __restrict__ wih16, int n1,
                           const float* __restrict__ whh_f, f16* __restrict__ whh16, int n2,
                           const float* __restrict__ h0, const float* __restrict__ c0,
                           float* __restrict__ hsave, float* __restrict__ csave,
                           unsigned* __restrict__ ht, unsigned* __restrict__ ctr, int layer) {
  int gid = blockIdx.x * 256 + threadIdx.x;
  int stride = gridDim.x * 256;
  for (int i = gid; i < n1; i += stride) wih16[i] = (f16)wih_f[i];
  for (int i = gid; i < n2; i += stride) whh16[i] = (f16)whh_f[i];
  for (int i = gid; i < 2 * NB * NH; i += stride) {
    int d = i >> 15, rem = i & 32767;
    float hv = h0[(size_t)(2 * layer + d) * NB * NH + rem];
    float cv = c0[(size_t)(2 * layer + d) * NB * NH + rem];
    hsave[i] = hv;
    csave[i] = cv;
    union { f16 f; unsigned short s; } hc; hc.f = (f16)hv;
    unsigned word = ((unsigned)(layer * NT) << 16) | hc.s;
    __hip_atomic_store(ht + (size_t)d * NB * NH + rem, word,
                       __ATOMIC_RELAXED, __HIP_MEMORY_SCOPE_AGENT);
  }
  if (gid < 256)
    __hip_atomic_store(ctr + gid, (unsigned)(layer * NT),
                       __ATOMIC_RELAXED, __HIP_MEMORY_SCOPE_AGENT);
}

// ---------------------------------------------------------------- gx GEMM body
// id = d*1024 + my*16 + nx  (d: dir, my: 128-row m-tile, nx: 128-col n-tile)
// sm: 16384B LDS scratch (As 8192 + Bs 8192) -- caller-provided so the hybrid
// kernel can UNION it with the rec arrays instead of summing allocations.
__device__ void gemm_body(const f16* __restrict__ A, const f16* __restrict__ W,
                          const float* __restrict__ bias, const int* __restrict__ lens,
                          f16* __restrict__ gxc, int K, int c0, int id, char* sm) {
  const int d = id >> 10;
  const int m0 = ((id >> 4) & 63) * 128;
  const int n0 = (id & 15) * 128;
  const f16* Wd = W + (size_t)d * NG * K;

  f16* As = (f16*)sm;            // 128*32 f16 = 8192B
  f16* Bs = (f16*)(sm + 8192);   // 128*32 f16 = 8192B

  const int tid = threadIdx.x, lane = tid & 63, wv = tid >> 6;
  const int wm = wv >> 1, wn = wv & 1;
  const int lrow = lane >> 2, lcol = (lane & 3) * 8;
  const int q = lane >> 4, nn = lane & 15;

  const f16* aptr[2];
  const f16* bptr[2];
#pragma unroll
  for (int i = 0; i < 2; ++i) {
    int ch = wv * 2 + i;
    int m = m0 + ch * 16 + lrow;  // chunk-local row = ct*64 + b
    int t = c0 + (m >> 6), b = m & 63;
    int tt = t;
    if (d) { tt = lens[b] - 1 - t; tt = tt < 0 ? 0 : (tt > NT - 1 ? NT - 1 : tt); }
    aptr[i] = A + (size_t)(tt * NB + b) * K + lcol;
    bptr[i] = Wd + (size_t)(n0 + ch * 16 + lrow) * K + lcol;
  }

  floatx4 acc[4][4] = {};
  for (int k0 = 0; k0 < K; k0 += 32) {
    __syncthreads();
#pragma unroll
    for (int i = 0; i < 2; ++i) {
      int ch = wv * 2 + i;
      load_lds16(aptr[i] + k0, As + ch * 512);
      load_lds16(bptr[i] + k0, Bs + ch * 512);
    }
    __syncthreads();
    half8 a[4], b[4];
#pragma unroll
    for (int f = 0; f < 4; ++f) {
      a[f] = *(const half8*)(As + (wm * 64 + f * 16 + nn) * 32 + q * 8);
      b[f] = *(const half8*)(Bs + (wn * 64 + f * 16 + nn) * 32 + q * 8);
    }
#pragma unroll
    for (int fm = 0; fm < 4; ++fm)
#pragma unroll
      for (int fn = 0; fn < 4; ++fn)
        acc[fm][fn] = __builtin_amdgcn_mfma_f32_16x16x32_f16(a[fm], b[fn], acc[fm][fn], 0, 0, 0);
  }

  f16* gxd = gxc + (size_t)d * CHUNK * NB * NG;
#pragma unroll
  for (int fn = 0; fn < 4; ++fn) {
    int col = n0 + wn * 64 + fn * 16 + nn;
    float bv = bias[d * NG + col];
#pragma unroll
    for (int fm = 0; fm < 4; ++fm) {
      int mb = m0 + wm * 64 + fm * 16 + q * 4;
#pragma unroll
      for (int r = 0; r < 4; ++r)
        gxd[(size_t)(mb + r) * NG + col] = (f16)(acc[fm][fn][r] + bv);
    }
  }
}

__global__ __launch_bounds__(256) void gemm_gx(const f16* __restrict__ A,
                                               const f16* __restrict__ W,
                                               const float* __restrict__ bias,
                                               const int* __restrict__ lens,
                                               f16* __restrict__ gxc, int K, int c0) {
  __shared__ __align__(16) char gsm[16384];
  gemm_body(A, W, bias, lens, gxc, K, c0,
            (int)(blockIdx.z * 1024 + blockIdx.y * 16 + blockIdx.x), gsm);
}

// ---------------------------------------------------------------- recurrence (one chunk)
// HYBRID GRID: blocks 0..255 = rec role (r4's verified free-running tagged
// protocol, unchanged; setprio(1) so latency-critical waves win CU issue
// arbitration over co-resident gemm waves); blocks 256..2303 = gemm role
// computing the NEXT chunk's gx into the ping-pong buffer. LDS is a single
// 37632B pool UNIONed between roles (r5 summed them: 54272B -> 2 gemm
// blocks/CU; union -> 4/CU). Rec blocks have low IDs -> dispatch first ->
// co-residency preserved.
__global__ __launch_bounds__(256, 1) void lstm_rec(
    const f16* __restrict__ gxc, const f16* __restrict__ whh,
    const int* __restrict__ lens, const int* __restrict__ cum,
    float* __restrict__ hsave, float* __restrict__ csave,
    unsigned* __restrict__ ht, unsigned* __restrict__ ctr,
    f16* __restrict__ Y, float* __restrict__ outp,
    float* __restrict__ hT, float* __restrict__ cT,
    int c0, int mode, int layer,
    const f16* __restrict__ Xg, const f16* __restrict__ wih,
    const float* __restrict__ biasg, f16* __restrict__ gxn, int Kg, int c0n) {
  // Unified LDS pool: rec uses As(33280B)+s_g(4352B)=37632B; gemm uses 16384B.
  __shared__ __align__(16) char smem[37632];
  if (blockIdx.x >= 256) {
    if (gxn) gemm_body(Xg, wih, biasg, lens, gxn, Kg, c0n, (int)blockIdx.x - 256, smem);
    return;
  }
  __builtin_amdgcn_s_setprio(1);  // rec waves outrank gemm waves on shared CUs
  unsigned (*As)[16][260] = (unsigned(*)[16][260])smem;          // [2][16][260] u32
  float (*s_g)[16][17] = (float(*)[16][17])(smem + 33280);       // [4][16][17] f32

  const int tid = threadIdx.x, lane = tid & 63, wv = tid >> 6;
  const int g = blockIdx.x & 7, w = blockIdx.x >> 3;
  const int dir = g & 1, bsl = g >> 1;
  const int q = lane >> 4, nn = lane & 15;

  const int maxlen = lens[bsl * 16];  // rows sorted desc: uniform group exit
  int nst = maxlen - c0;
  if (nst <= 0) return;
  if (nst > CHUNK) nst = CHUNK;

  const int jbase = w * 16 + wv * 4;
  const int coln = (nn >> 2) * NH + jbase + (nn & 3);
  const f16* whd = whh + (size_t)dir * NG * NH;
  half8 bf[16];
#pragma unroll
  for (int s = 0; s < 16; ++s) {
    bf[s] = *(const half8*)(whd + (size_t)coln * NH + s * 32 + q * 8);
    asm volatile("" : "+v"(bf[s]));  // opaque def: discourage remat
  }

  const int b_e = bsl * 16 + nn;
  const int jglob = jbase + q;
  const int lene = lens[b_e];
  const int brow = bsl * 16 + q * 4;
  const int lidx = (dir * NB + b_e) * NH + jglob;
  float h = hsave[lidx], c = csave[lidx];

  const f16* gxd = gxc + (size_t)dir * CHUNK * NB * NG;
  const int ebase = layer * NT;  // epochs monotonic across chunks & layers

  const unsigned* cslot = ctr + (size_t)g * 32 + (lane & 31);

  for (int ct = 0; ct < nst; ++ct) {
    const int t = c0 + ct;
    const int e = ebase + t;      // tag required on consumed h
    const int par = t & 1;

    // gx loads issued early (HBM latency overlaps the wait)
    float gxv[4];
#pragma unroll
    for (int r = 0; r < 4; ++r)
      gxv[r] = (float)gxd[(size_t)(ct * NB + brow + r) * NG + coln];

    // ---- cheap readiness gate: 1 coalesced line/wave/iteration ----
    {
      const unsigned* cp = cslot + par * 256;
      int it = 0;
      for (;;) {
        unsigned cv = __hip_atomic_load(cp, __ATOMIC_RELAXED, __HIP_MEMORY_SCOPE_AGENT);
        if (__ballot((int)cv >= e) == ~0ull) break;
        if (++it > 200000) break;  // fail as wrong-answer, not hang
        __builtin_amdgcn_s_sleep(1);  // 64cy backoff: cut MALL poll contention
      }
    }

    // ---- flat data pass, tag-verified (full MLP: 16 u64 in flight) ----
    // lane (q,nn): row nn, words k = wv*128 + s*32 + q*8 .. +8
    const unsigned long long* p64 =
        (const unsigned long long*)(ht + ((size_t)(par * 2 + dir) * NB + bsl * 16 + nn) * NH +
                                    wv * 128 + q * 8);
    unsigned long long wb[16];
    {
      int it = 0;
      for (;;) {
#pragma unroll
        for (int i = 0; i < 16; ++i)
          wb[i] = __hip_atomic_load(p64 + (i >> 2) * 16 + (i & 3), __ATOMIC_RELAXED,
                                    __HIP_MEMORY_SCOPE_AGENT);
        unsigned tg = 0xffffu;
#pragma unroll
        for (int i = 0; i < 16; ++i) {
          tg &= (unsigned)(wb[i] >> 16) & 0xffffu;
          tg &= (unsigned)(wb[i] >> 48);
        }
        // words hold only epoch e or e-2 (ping-pong parity); AND(e-2, e) < e,
        // AND(all e) == e -> exact freshness test.
        if (__ballot(tg >= (unsigned)e) == ~0ull) break;
        if (++it > 50000) break;  // fail as wrong-answer, not hang
        __builtin_amdgcn_s_sleep(1);
      }
    }

    // ---- extract f16 payloads -> LDS A tile ----
#pragma unroll
    for (int s = 0; s < 4; ++s) {
      unsigned d0 = (unsigned)(wb[4 * s + 0] & 0xffffu) | ((unsigned)(wb[4 * s + 0] >> 32) << 16);
      unsigned d1 = (unsigned)(wb[4 * s + 1] & 0xffffu) | ((unsigned)(wb[4 * s + 1] >> 32) << 16);
      unsigned d2 = (unsigned)(wb[4 * s + 2] & 0xffffu) | ((unsigned)(wb[4 * s + 2] >> 32) << 16);
      unsigned d3 = (unsigned)(wb[4 * s + 3] & 0xffffu) | ((unsigned)(wb[4 * s + 3] >> 32) << 16);
      *(u32x4*)&As[par][nn][wv * 64 + s * 16 + q * 4] = (u32x4){d0, d1, d2, d3};
    }
    __syncthreads();  // the ONLY per-step barrier (block-local)

    // ---- MFMA: 16 k-slabs from LDS ----
    floatx4 acc0 = {0.f, 0.f, 0.f, 0.f}, acc1 = {0.f, 0.f, 0.f, 0.f};
#pragma unroll
    for (int s = 0; s < 8; ++s) {
      half8 a0 = *(const half8*)&As[par][nn][(2 * s) * 16 + q * 4];
      half8 a1 = *(const half8*)&As[par][nn][(2 * s + 1) * 16 + q * 4];
      acc0 = __builtin_amdgcn_mfma_f32_16x16x32_f16(a0, bf[2 * s], acc0, 0, 0, 0);
      acc1 = __builtin_amdgcn_mfma_f32_16x16x32_f16(a1, bf[2 * s + 1], acc1, 0, 0, 0);
    }
#pragma unroll
    for (int r4 = 0; r4 < 4; ++r4) s_g[wv][q * 4 + r4][nn] = acc0[r4] + acc1[r4] + gxv[r4];
    // s_g[wv] is wave-private: ds ordering (lgkmcnt) suffices, no barrier.

    const bool act = (t < lene);
    if (act) {
      float gi = s_g[wv][nn][q];
      float gf = s_g[wv][nn][4 + q];
      float gg = s_g[wv][nn][8 + q];
      float go = s_g[wv][nn][12 + q];
      c = sigf(gf) * c + sigf(gi) * tanhfast(gg);
      h = sigf(go) * tanhfast(c);
    }
    // ---- tagged publish (the sync) ----
    union { f16 f; unsigned short s; } hc; hc.f = (f16)h;
    unsigned word = ((unsigned)(e + 1) << 16) | hc.s;
    __hip_atomic_store(ht + ((size_t)(((t + 1) & 1) * 2 + dir) * NB + b_e) * NH + jglob,
                       word, __ATOMIC_RELAXED, __HIP_MEMORY_SCOPE_AGENT);
    // ready-counter bump: racy-early HINT (tags remain the proof)
    if (tid == 0)
      __hip_atomic_store(ctr + (size_t)(((t + 1) & 1) * 256 + g * 32 + w), (unsigned)(e + 1),
                         __ATOMIC_RELAXED, __HIP_MEMORY_SCOPE_AGENT);
    // Y / packed-out stores: fire-and-forget, drain under later waits
    if (mode == 0) {
      int tp = act ? (dir ? (lene - 1 - t) : t) : t;
      Y[(size_t)(tp * NB + b_e) * (2 * NH) + dir * NH + jglob] = act ? (f16)h : (f16)0.f;
    } else if (act) {
      int tp = dir ? (lene - 1 - t) : t;
      outp[(size_t)(cum[tp] + b_e) * (2 * NH) + dir * NH + jglob] = h;
    }
  }

  hsave[lidx] = h;
  csave[lidx] = c;
  const int sidx = ((2 * layer + dir) * NB + b_e) * NH + jglob;
  hT[sidx] = h;
  cT[sidx] = c;
}

// ---------------------------------------------------------------- host
extern "C" void kernel_launch(void* const* d_in, const int* in_sizes, int n_in,
                              void* d_out, int out_size, void* d_ws, size_t ws_size,
                              hipStream_t stream) {
  const float* data  = (const float*)d_in[0];
  const float* h0    = (const float*)d_in[1];
  const float* c0    = (const float*)d_in[2];
  const float* w_ih0 = (const float*)d_in[3];
  const float* w_hh0 = (const float*)d_in[4];
  const float* b0    = (const float*)d_in[5];
  const float* w_ihr = (const float*)d_in[6];
  const float* w_hhr = (const float*)d_in[7];
  const float* b_r   = (const float*)d_in[8];
  const int* bs_raw  = (const int*)d_in[9];
  const int* pidx    = (const int*)d_in[10];
  const int nrows = in_sizes[0] / 512;
  float* out = (float*)d_out;

  // Y0 (layer-0 output, f16, 67MB) aliases d_out's packed-out region (dead by l2).
  f16* Y0 = (f16*)d_out;
  float* hT = out + (size_t)nrows * 1024;
  float* cT = hT + (size_t)6 * NB * NH;

  char* p = (char*)d_ws;
  auto take = [&](size_t bytes) {
    char* r = p;
    p += (bytes + 255) & ~(size_t)255;
    return (void*)r;
  };
  const size_t gsz = (size_t)2 * CHUNK * NB * NG * 2;        // 67 MB per gx buffer
  f16* gxcA  = (f16*)take(gsz);
  f16* Y1    = (f16*)take((size_t)NT * NB * 1024 * 2);       // 67 MB
  f16* X0    = Y1;  // alias: X0 dead after l0 gemm; Y1 first written by l1 rec
  f16* wih16 = (f16*)take((size_t)2 * NG * 1024 * 2);
  f16* whh16 = (f16*)take((size_t)2 * NG * NH * 2);
  unsigned* ht = (unsigned*)take((size_t)2 * 2 * NB * NH * 4);  // tagged h, 512KB
  unsigned* ctr = (unsigned*)take((size_t)2 * 8 * 32 * 4);      // ready counters, 2KB
  float* hsave = (float*)take((size_t)2 * NB * NH * 4);
  float* csave = (float*)take((size_t)2 * NB * NH * 4);
  int* lens = (int*)take(256);
  int* cum  = (int*)take(NT * 4);
  // second gx buffer (ping-pong for fused next-chunk gemm) -- only if it fits
  f16* gxcB = nullptr;
  if ((size_t)(p - (char*)d_ws) + gsz <= ws_size) gxcB = (f16*)take(gsz);
  const bool fuse = (gxcB != nullptr);

  prep_meta<<<1, 256, 0, stream>>>(bs_raw, lens, cum);
  (void)hipMemsetAsync(X0, 0, (size_t)NT * NB * 512 * 2, stream);
  (void)hipMemsetAsync(ht, 0, (size_t)2 * 2 * NB * NH * 4, stream);  // tags 0 (< any epoch)
  (void)hipMemsetAsync(ctr, 0, (size_t)2 * 8 * 32 * 4, stream);      // ctr 0 (< any epoch)
  scatter_rows<<<nrows, 256, 0, stream>>>(data, pidx, X0);

  for (int l = 0; l < 3; ++l) {
    const float* wih_f = (l == 0) ? w_ih0 : w_ihr + (size_t)(l - 1) * 2 * NG * 1024;
    const float* whh_f = (l == 0) ? w_hh0 : w_hhr + (size_t)(l - 1) * 2 * NG * NH;
    const float* bias  = (l == 0) ? b0 : b_r + (size_t)(l - 1) * 2 * NG;
    const int K = (l == 0) ? 512 : 1024;
    const f16* Xl = (l == 0) ? X0 : ((l == 1) ? Y0 : Y1);
    f16* Yl = (l == 0) ? Y0 : Y1;
    prep_layer<<<512, 256, 0, stream>>>(wih_f, wih16, 2 * NG * K, whh_f, whh16,
                                        2 * NG * NH, h0, c0, hsave, csave, ht, ctr, l);
    for (int c = 0; c < 4; ++c) {
      f16* gcur = fuse ? ((c & 1) ? gxcB : gxcA) : gxcA;
      if (c == 0 || !fuse)
        gemm_gx<<<dim3(16, 64, 2), 256, 0, stream>>>(Xl, wih16, bias, lens, gcur, K, c * CHUNK);
      const bool g_on = fuse && (c < 3);
      f16* gnext = g_on ? (((c + 1) & 1) ? gxcB : gxcA) : nullptr;
      const int grid = g_on ? 2304 : 256;
      lstm_rec<<<grid, 256, 0, stream>>>(gcur, whh16, lens, cum, hsave, csave, ht, ctr, Yl,
                                         out, hT, cT, c * CHUNK, (l == 2) ? 1 : 0, l,
                                         Xl, wih16, bias, gnext, K, (c + 1) * CHUNK);
    }
  }
}